// Round 7
// baseline (431.274 us; speedup 1.0000x reference)
//
#include <hip/hip_runtime.h>
#include <hip/hip_bf16.h>
#include <math.h>

#define B_N 8192
#define T_N 4
#define D_N 1024
#define NB  32                 // 8192/256 row/col blocks
#define NT  16                 // 1024/64 K-tiles
#define TRI (NB * (NB + 1) / 2)  // 528 upper-triangle blocks per view (528 = 8*66)

typedef __bf16 bf16x8 __attribute__((ext_vector_type(8)));
typedef float f32x4 __attribute__((ext_vector_type(4)));

// ---- order-preserving float <-> uint map ----
__device__ inline unsigned int f2u_ord(float f) {
    unsigned int b = __float_as_uint(f);
    return (b & 0x80000000u) ? ~b : (b | 0x80000000u);
}
__device__ inline float u2f_ord(unsigned int u) {
    unsigned int b = (u & 0x80000000u) ? (u & 0x7FFFFFFFu) : ~u;
    return __uint_as_float(b);
}

// round-to-nearest-even f32 -> bf16
__device__ inline unsigned short f2bf(float f) {
    unsigned int u = __float_as_uint(f);
    unsigned int r = (u + 0x7FFFu + ((u >> 16) & 1u)) >> 16;
    return (unsigned short)r;
}

__global__ __launch_bounds__(256) void init_rowmax_kernel(unsigned int* __restrict__ rowmax) {
    int i = blockIdx.x * 256 + threadIdx.x;
    if (i < T_N * B_N) rowmax[i] = 0u;
}

// in: [B][T][D] f32 ; out xn: [T][B][D] bf16 (normalized rows)
__global__ __launch_bounds__(256) void norm_kernel(const float* __restrict__ in,
                                                   unsigned short* __restrict__ xn) {
    const int row  = blockIdx.x * 4 + (threadIdx.x >> 6);
    const int lane = threadIdx.x & 63;
    const int b = row >> 2;
    const int t = row & 3;
    const float* src = in + (size_t)row * D_N;

    float4 v[4];
    float ss = 0.f;
#pragma unroll
    for (int i = 0; i < 4; ++i) {
        v[i] = reinterpret_cast<const float4*>(src)[lane + 64 * i];
        ss += v[i].x * v[i].x + v[i].y * v[i].y + v[i].z * v[i].z + v[i].w * v[i].w;
    }
#pragma unroll
    for (int off = 32; off; off >>= 1) ss += __shfl_xor(ss, off, 64);
    const float rn = 1.0f / fmaxf(sqrtf(ss), 1e-12f);

    unsigned short* dst = xn + ((size_t)t * B_N + b) * D_N;
#pragma unroll
    for (int i = 0; i < 4; ++i) {
        ushort4 o;
        o.x = f2bf(v[i].x * rn);
        o.y = f2bf(v[i].y * rn);
        o.z = f2bf(v[i].z * rn);
        o.w = f2bf(v[i].w * rn);
        reinterpret_cast<ushort4*>(dst)[lane + 64 * i] = o;
    }
}

#define GLOAD_LDS16(g, l)                                                              \
    __builtin_amdgcn_global_load_lds(                                                  \
        (const __attribute__((address_space(1))) unsigned int*)(g),                    \
        (__attribute__((address_space(3))) unsigned int*)(l), 16, 0, 0)

// Gram matrix upper-triangle, 256x256 tile, BK=64, 8 waves (2M x 4N), 4-phase
// fragment-retention schedule (R4 base, ledger audited clean):
//  P1: read A0(8)+B0(4), stage u0'; gate vmcnt(4) [retire u3]
//  P2: read B1(4),        stage u2'; gate vmcnt(4) [retire u1]
//  P3: read A1(8),        stage u3'; no gate
//  P4: (no reads),        stage u1'; gate vmcnt(4) [retire u0',u2']
// Phase interior (m201-style pure burst): BARRIER; lgkmcnt(0); sched_barrier(0);
// setprio(1); 16 MFMA; setprio(0); gate; BARRIER.
// LDS chunk-XOR swizzle (chunk ^= row&7), source-side + read-side.
__global__ __launch_bounds__(512, 2) void gemm_rowmax_kernel(const unsigned short* __restrict__ xn,
                                                             unsigned int* __restrict__ rowmax) {
    const int t = blockIdx.z;
    // XCD-chunked bijective swizzle: 528 = 8 * 66; consecutive triangle ids
    // (sharing the A row-panel) land on the SAME XCD's L2.
    const int bid = blockIdx.x;
    int l = (bid & 7) * (TRI / 8) + (bid >> 3);
    // triangle decode: linear -> (by, bx), bx >= by
    int by = 0;
    while (l >= NB - by) { l -= NB - by; ++by; }
    const int bx = by + l;

    const unsigned short* X = xn + (size_t)t * B_N * D_N;

    __shared__ __align__(16) unsigned short lds[65536];  // 128 KiB: [2 buf][A 16K el | B 16K el]

    const int tid  = threadIdx.x;
    const int lane = tid & 63;
    const int wv   = tid >> 6;   // 0..7
    const int wr   = wv >> 2;    // M half (128 rows)
    const int wcn  = wv & 3;     // N quarter (64 cols)

    // staging: wave-load = 8 rows x 8 chunks(16B); source chunk pre-swizzled
    const int lrow8  = lane >> 3;
    const int gchunk = (lane & 7) ^ lrow8;
    const size_t aGR = (size_t)by * 256;
    const size_t bGR = (size_t)bx * 256;
    const int idx0 = wv * 2, idx1 = wv * 2 + 1;
    const int rB0 = (idx0 >> 2) * 64 + (idx0 & 3) * 8;
    const int rB1 = (idx1 >> 2) * 64 + (idx1 & 3) * 8;

    // fragment read bases; read-side swizzle: chunk = kk ^ (row&7), row&7 == lane&7
    const int arBase = wr * 128 + (lane & 15);
    const int brBase = wcn * 64 + (lane & 15);
    const int csw0 = (((lane >> 4)) ^ (lane & 7)) * 8;
    const int csw1 = (((lane >> 4) + 4) ^ (lane & 7)) * 8;

    f32x4 acc[8][4];
#pragma unroll
    for (int m = 0; m < 8; ++m)
#pragma unroll
        for (int n = 0; n < 4; ++n) acc[m][n] = (f32x4){0.f, 0.f, 0.f, 0.f};

#define STAGE_A(bufw, r0, kc)                                                           \
    GLOAD_LDS16(X + ((aGR + (r0) + lrow8) << 10) + (kc) + gchunk * 8,                   \
                &lds[(bufw) + (unsigned)(r0) * 64])
#define STAGE_B(bufw, r0, kc)                                                           \
    GLOAD_LDS16(X + ((bGR + (r0) + lrow8) << 10) + (kc) + gchunk * 8,                   \
                &lds[(bufw) + 16384u + (unsigned)(r0) * 64])

#define LOAD_A(MQ)                                                                      \
    _Pragma("unroll")                                                                   \
    for (int mf = 0; mf < 4; ++mf) {                                                    \
        const unsigned r = bufR + (unsigned)(arBase + (MQ) * 64 + mf * 16) * 64;        \
        aF0[mf] = *reinterpret_cast<const bf16x8*>(&lds[r + csw0]);                     \
        aF1[mf] = *reinterpret_cast<const bf16x8*>(&lds[r + csw1]);                     \
    }
#define LOAD_B(NQ)                                                                      \
    _Pragma("unroll")                                                                   \
    for (int nf = 0; nf < 2; ++nf) {                                                    \
        const unsigned r = bufR + 16384u + (unsigned)(brBase + (NQ) * 32 + nf * 16) * 64; \
        bF0[(NQ) * 2 + nf] = *reinterpret_cast<const bf16x8*>(&lds[r + csw0]);          \
        bF1[(NQ) * 2 + nf] = *reinterpret_cast<const bf16x8*>(&lds[r + csw1]);          \
    }
#define MFMA_Q(MQ, NQ)                                                                  \
    _Pragma("unroll")                                                                   \
    for (int mf = 0; mf < 4; ++mf)                                                      \
        _Pragma("unroll")                                                               \
        for (int nf = 0; nf < 2; ++nf) {                                                \
            acc[(MQ) * 4 + mf][(NQ) * 2 + nf] = __builtin_amdgcn_mfma_f32_16x16x32_bf16( \
                aF0[mf], bF0[(NQ) * 2 + nf], acc[(MQ) * 4 + mf][(NQ) * 2 + nf], 0, 0, 0); \
            acc[(MQ) * 4 + mf][(NQ) * 2 + nf] = __builtin_amdgcn_mfma_f32_16x16x32_bf16( \
                aF1[mf], bF1[(NQ) * 2 + nf], acc[(MQ) * 4 + mf][(NQ) * 2 + nf], 0, 0, 0); \
        }

#define BARRIER asm volatile("s_barrier" ::: "memory")
#define VMCNT(N) asm volatile("s_waitcnt vmcnt(" #N ")" ::: "memory")
#define PUREBURST asm volatile("s_waitcnt lgkmcnt(0)" ::: "memory"); __builtin_amdgcn_sched_barrier(0)

    // prologue: stage tile 0 units in issue order u0, u2, u3, u1
    STAGE_A(0u, wv * 8, 0);        STAGE_A(0u, 128 + wv * 8, 0);   // u0 (A MQ0)
    STAGE_B(0u, rB0, 0);           STAGE_B(0u, rB1, 0);            // u2 (B NQ0)
    STAGE_B(0u, rB0 + 32, 0);      STAGE_B(0u, rB1 + 32, 0);       // u3 (B NQ1)
    STAGE_A(0u, 64 + wv * 8, 0);   STAGE_A(0u, 192 + wv * 8, 0);   // u1 (A MQ1)
    VMCNT(4);  // u0,u2 retired; entering loop: outstanding = u3,u1 (4)
    BARRIER;

    for (int kt = 0; kt < NT; ++kt) {
        const bool haveNext = (kt + 1) < NT;
        const unsigned bufR = (kt & 1) ? 32768u : 0u;
        const unsigned bufW = ((kt + 1) & 1) ? 32768u : 0u;
        const int kc = (kt + 1) * 64;

        bf16x8 aF0[4], aF1[4], bF0[4], bF1[4];

        // ---- P1: (MQ0,NQ0); stage u0'; gate retires u3(cur) ----
        LOAD_A(0); LOAD_B(0);
        if (haveNext) { STAGE_A(bufW, wv * 8, kc); STAGE_A(bufW, 128 + wv * 8, kc); }
        BARRIER;
        PUREBURST;
        __builtin_amdgcn_s_setprio(1);
        MFMA_Q(0, 0);
        __builtin_amdgcn_s_setprio(0);
        if (haveNext) { VMCNT(4); } else { VMCNT(2); }
        BARRIER;

        // ---- P2: (MQ0,NQ1); stage u2'; gate retires u1(cur) ----
        LOAD_B(1);
        if (haveNext) { STAGE_B(bufW, rB0, kc); STAGE_B(bufW, rB1, kc); }
        BARRIER;
        PUREBURST;
        __builtin_amdgcn_s_setprio(1);
        MFMA_Q(0, 1);
        __builtin_amdgcn_s_setprio(0);
        if (haveNext) { VMCNT(4); } else { VMCNT(0); }
        BARRIER;

        // ---- P3: (MQ1,NQ0); stage u3'; no gate ----
        LOAD_A(1);
        if (haveNext) { STAGE_B(bufW, rB0 + 32, kc); STAGE_B(bufW, rB1 + 32, kc); }
        BARRIER;
        PUREBURST;
        __builtin_amdgcn_s_setprio(1);
        MFMA_Q(1, 0);
        __builtin_amdgcn_s_setprio(0);
        BARRIER;

        // ---- P4: (MQ1,NQ1); stage u1'; gate retires u0',u2' ----
        if (haveNext) { STAGE_A(bufW, 64 + wv * 8, kc); STAGE_A(bufW, 192 + wv * 8, kc); }
        BARRIER;
        PUREBURST;
        __builtin_amdgcn_s_setprio(1);
        MFMA_Q(1, 1);
        __builtin_amdgcn_s_setprio(0);
        if (haveNext) { VMCNT(4); }
        BARRIER;
    }

    // epilogue: C/D layout col = lane&15, row = (lane>>4)*4 + reg
    const int rbase = by * 256 + wr * 128;
    const int cbase = bx * 256 + wcn * 64;
    unsigned int* rm = rowmax + t * B_N;

    // row-max over this wave's 64 cols (diag excluded)
#pragma unroll
    for (int m = 0; m < 8; ++m) {
#pragma unroll
        for (int r = 0; r < 4; ++r) {
            const int row = rbase + m * 16 + (lane >> 4) * 4 + r;
            float mx = -2.0f;
#pragma unroll
            for (int n = 0; n < 4; ++n) {
                const int col = cbase + n * 16 + (lane & 15);
                float v = acc[m][n][r];
                if (col != row) mx = fmaxf(mx, v);
            }
#pragma unroll
            for (int off = 1; off < 16; off <<= 1) mx = fmaxf(mx, __shfl_xor(mx, off, 64));
            if ((lane & 15) == 0) atomicMax(&rm[row], f2u_ord(mx));
        }
    }
    // col-max over this wave's 128 rows (covers mirrored lower-triangle block)
#pragma unroll
    for (int n = 0; n < 4; ++n) {
        const int col = cbase + n * 16 + (lane & 15);
        float mx = -2.0f;
#pragma unroll
        for (int m = 0; m < 8; ++m)
#pragma unroll
            for (int r = 0; r < 4; ++r) {
                const int row = rbase + m * 16 + (lane >> 4) * 4 + r;
                float v = acc[m][n][r];
                if (col != row) mx = fmaxf(mx, v);
            }
        mx = fmaxf(mx, __shfl_xor(mx, 16, 64));
        mx = fmaxf(mx, __shfl_xor(mx, 32, 64));
        if ((lane >> 4) == 0) atomicMax(&rm[col], f2u_ord(mx));
    }
#undef MFMA_Q
#undef LOAD_A
#undef LOAD_B
#undef STAGE_A
#undef STAGE_B
#undef BARRIER
#undef VMCNT
#undef PUREBURST
}

__global__ __launch_bounds__(256) void finish_kernel(const unsigned int* __restrict__ rowmax,
                                                     float* __restrict__ out) {
    __shared__ float sbuf[4];
    float s = 0.f;
    for (int i = threadIdx.x; i < T_N * B_N; i += 256) {
        float m  = u2f_ord(rowmax[i]);
        float d2 = fmaxf(2.0f - 2.0f * m, 0.0f);
        s += logf(sqrtf(d2) + 1e-12f);
    }
#pragma unroll
    for (int off = 32; off; off >>= 1) s += __shfl_xor(s, off, 64);
    const int w = threadIdx.x >> 6;
    if ((threadIdx.x & 63) == 0) sbuf[w] = s;
    __syncthreads();
    if (threadIdx.x == 0) {
        out[0] = -(sbuf[0] + sbuf[1] + sbuf[2] + sbuf[3]) / (float)(T_N * B_N);
    }
}

extern "C" void kernel_launch(void* const* d_in, const int* in_sizes, int n_in,
                              void* d_out, int out_size, void* d_ws, size_t ws_size,
                              hipStream_t stream) {
    const float* in = (const float*)d_in[0];
    unsigned short* xn = (unsigned short*)d_ws;  // 64 MB bf16 [T][B][D]
    unsigned int* rowmax = (unsigned int*)((char*)d_ws + (size_t)T_N * B_N * D_N * 2);
    float* out = (float*)d_out;

    init_rowmax_kernel<<<(T_N * B_N + 255) / 256, 256, 0, stream>>>(rowmax);
    norm_kernel<<<(B_N * T_N) / 4, 256, 0, stream>>>(in, xn);
    dim3 g(TRI, 1, T_N);
    gemm_rowmax_kernel<<<g, 512, 0, stream>>>(xn, rowmax);
    finish_kernel<<<1, 256, 0, stream>>>(rowmax, out);
}

// Round 8
// 425.144 us; speedup vs baseline: 1.0144x; 1.0144x over previous
//
#include <hip/hip_runtime.h>
#include <hip/hip_bf16.h>
#include <math.h>

#define B_N 8192
#define T_N 4
#define D_N 1024
#define NB  32                 // 8192/256 row/col blocks
#define NT  16                 // 1024/64 K-tiles
#define TRI (NB * (NB + 1) / 2)  // 528 upper-triangle blocks per view (528 = 8*66)

typedef __bf16 bf16x8 __attribute__((ext_vector_type(8)));
typedef float f32x4 __attribute__((ext_vector_type(4)));

// ---- order-preserving float <-> uint map ----
__device__ inline unsigned int f2u_ord(float f) {
    unsigned int b = __float_as_uint(f);
    return (b & 0x80000000u) ? ~b : (b | 0x80000000u);
}
__device__ inline float u2f_ord(unsigned int u) {
    unsigned int b = (u & 0x80000000u) ? (u & 0x7FFFFFFFu) : ~u;
    return __uint_as_float(b);
}

// round-to-nearest-even f32 -> bf16
__device__ inline unsigned short f2bf(float f) {
    unsigned int u = __float_as_uint(f);
    unsigned int r = (u + 0x7FFFu + ((u >> 16) & 1u)) >> 16;
    return (unsigned short)r;
}

__global__ __launch_bounds__(256) void init_rowmax_kernel(unsigned int* __restrict__ rowmax) {
    int i = blockIdx.x * 256 + threadIdx.x;
    if (i < T_N * B_N) rowmax[i] = 0u;
}

// in: [B][T][D] f32 ; out xn: [T][B][D] bf16 (normalized rows)
__global__ __launch_bounds__(256) void norm_kernel(const float* __restrict__ in,
                                                   unsigned short* __restrict__ xn) {
    const int row  = blockIdx.x * 4 + (threadIdx.x >> 6);
    const int lane = threadIdx.x & 63;
    const int b = row >> 2;
    const int t = row & 3;
    const float* src = in + (size_t)row * D_N;

    float4 v[4];
    float ss = 0.f;
#pragma unroll
    for (int i = 0; i < 4; ++i) {
        v[i] = reinterpret_cast<const float4*>(src)[lane + 64 * i];
        ss += v[i].x * v[i].x + v[i].y * v[i].y + v[i].z * v[i].z + v[i].w * v[i].w;
    }
#pragma unroll
    for (int off = 32; off; off >>= 1) ss += __shfl_xor(ss, off, 64);
    const float rn = 1.0f / fmaxf(sqrtf(ss), 1e-12f);

    unsigned short* dst = xn + ((size_t)t * B_N + b) * D_N;
#pragma unroll
    for (int i = 0; i < 4; ++i) {
        ushort4 o;
        o.x = f2bf(v[i].x * rn);
        o.y = f2bf(v[i].y * rn);
        o.z = f2bf(v[i].z * rn);
        o.w = f2bf(v[i].w * rn);
        reinterpret_cast<ushort4*>(dst)[lane + 64 * i] = o;
    }
}

#define GLOAD_LDS16(g, l)                                                              \
    __builtin_amdgcn_global_load_lds(                                                  \
        (const __attribute__((address_space(1))) unsigned int*)(g),                    \
        (__attribute__((address_space(3))) unsigned int*)(l), 16, 0, 0)

// Gram matrix upper-triangle, 256x256 tile, BK=64, 8 waves (2M x 4N).
// READ-AHEAD pipeline: fragment reads for quadrant Qp are issued in phase p-1,
// so no MFMA burst ever waits on just-issued ds_reads; the LDS pipe fills
// underneath the MFMA bursts. Gates sit just before each read-issue:
//   P1: stage u0'; vmcnt(4)[u3 ready]; BAR; issue B1 reads;  MFMA Q00
//   P2: stage u2'; vmcnt(4)[u1 ready]; BAR; issue A1 reads;  MFMA Q01
//   P3: stage u3';                          (no reads)       MFMA Q10
//   P4: stage u1'; vmcnt(4)[u0',u2'];  BAR; issue A0',B0' (bufW!); MFMA Q11
// 3 barriers per K-tile. Cross-tile read-ahead is safe: bufW reads happen
// only after the collective vmcnt(4)+BAR that retires u0',u2' on all waves.
// LDS chunk-XOR swizzle (chunk ^= row&7), source-side + read-side.
__global__ __launch_bounds__(512, 2) void gemm_rowmax_kernel(const unsigned short* __restrict__ xn,
                                                             unsigned int* __restrict__ rowmax) {
    const int t = blockIdx.z;
    // XCD-chunked bijective swizzle: 528 = 8 * 66
    const int bid = blockIdx.x;
    int l = (bid & 7) * (TRI / 8) + (bid >> 3);
    int by = 0;
    while (l >= NB - by) { l -= NB - by; ++by; }
    const int bx = by + l;

    const unsigned short* X = xn + (size_t)t * B_N * D_N;

    __shared__ __align__(16) unsigned short lds[65536];  // 128 KiB: [2 buf][A 16K el | B 16K el]

    const int tid  = threadIdx.x;
    const int lane = tid & 63;
    const int wv   = tid >> 6;   // 0..7
    const int wr   = wv >> 2;    // M half (128 rows)
    const int wcn  = wv & 3;     // N quarter (64 cols)

    // staging: wave-load = 8 rows x 8 chunks(16B); source chunk pre-swizzled
    const int lrow8  = lane >> 3;
    const int gchunk = (lane & 7) ^ lrow8;
    const size_t aGR = (size_t)by * 256;
    const size_t bGR = (size_t)bx * 256;
    const int idx0 = wv * 2, idx1 = wv * 2 + 1;
    const int rB0 = (idx0 >> 2) * 64 + (idx0 & 3) * 8;
    const int rB1 = (idx1 >> 2) * 64 + (idx1 & 3) * 8;

    // fragment read bases; read-side swizzle: chunk = kk ^ (row&7), row&7 == lane&7
    const int arBase = wr * 128 + (lane & 15);
    const int brBase = wcn * 64 + (lane & 15);
    const int csw0 = (((lane >> 4)) ^ (lane & 7)) * 8;
    const int csw1 = (((lane >> 4) + 4) ^ (lane & 7)) * 8;

    f32x4 acc[8][4];
#pragma unroll
    for (int m = 0; m < 8; ++m)
#pragma unroll
        for (int n = 0; n < 4; ++n) acc[m][n] = (f32x4){0.f, 0.f, 0.f, 0.f};

#define STAGE_A(bufw, r0, kc)                                                           \
    GLOAD_LDS16(X + ((aGR + (r0) + lrow8) << 10) + (kc) + gchunk * 8,                   \
                &lds[(bufw) + (unsigned)(r0) * 64])
#define STAGE_B(bufw, r0, kc)                                                           \
    GLOAD_LDS16(X + ((bGR + (r0) + lrow8) << 10) + (kc) + gchunk * 8,                   \
                &lds[(bufw) + 16384u + (unsigned)(r0) * 64])

#define LOAD_AS(AF0, AF1, MQ, BUF)                                                      \
    _Pragma("unroll")                                                                   \
    for (int mf = 0; mf < 4; ++mf) {                                                    \
        const unsigned r = (BUF) + (unsigned)(arBase + (MQ) * 64 + mf * 16) * 64;       \
        AF0[mf] = *reinterpret_cast<const bf16x8*>(&lds[r + csw0]);                     \
        AF1[mf] = *reinterpret_cast<const bf16x8*>(&lds[r + csw1]);                     \
    }
#define LOAD_BS(NQ, BUF)                                                                \
    _Pragma("unroll")                                                                   \
    for (int nf = 0; nf < 2; ++nf) {                                                    \
        const unsigned r = (BUF) + 16384u + (unsigned)(brBase + (NQ) * 32 + nf * 16) * 64; \
        bF0[(NQ) * 2 + nf] = *reinterpret_cast<const bf16x8*>(&lds[r + csw0]);          \
        bF1[(NQ) * 2 + nf] = *reinterpret_cast<const bf16x8*>(&lds[r + csw1]);          \
    }
#define MFMA_Q(AF0, AF1, MQ, NQ)                                                        \
    __builtin_amdgcn_s_setprio(1);                                                      \
    _Pragma("unroll")                                                                   \
    for (int mf = 0; mf < 4; ++mf)                                                      \
        _Pragma("unroll")                                                               \
        for (int nf = 0; nf < 2; ++nf) {                                                \
            acc[(MQ) * 4 + mf][(NQ) * 2 + nf] = __builtin_amdgcn_mfma_f32_16x16x32_bf16( \
                AF0[mf], bF0[(NQ) * 2 + nf], acc[(MQ) * 4 + mf][(NQ) * 2 + nf], 0, 0, 0); \
            acc[(MQ) * 4 + mf][(NQ) * 2 + nf] = __builtin_amdgcn_mfma_f32_16x16x32_bf16( \
                AF1[mf], bF1[(NQ) * 2 + nf], acc[(MQ) * 4 + mf][(NQ) * 2 + nf], 0, 0, 0); \
        }                                                                               \
    __builtin_amdgcn_s_setprio(0);

#define BARRIER asm volatile("s_barrier" ::: "memory")
#define VMCNT(N) asm volatile("s_waitcnt vmcnt(" #N ")" ::: "memory")

    // persistent fragment state (loop-carried across phases/tiles)
    bf16x8 a0F0[4], a0F1[4];   // A slot 0 (MQ0 rows)
    bf16x8 a1F0[4], a1F1[4];   // A slot 1 (MQ1 rows)
    bf16x8 bF0[4], bF1[4];     // B frags: idx 0,1 = B0(NQ0); 2,3 = B1(NQ1)

    // prologue: stage tile 0 units in issue order u0, u2, u3, u1
    STAGE_A(0u, wv * 8, 0);        STAGE_A(0u, 128 + wv * 8, 0);   // u0 (A MQ0)
    STAGE_B(0u, rB0, 0);           STAGE_B(0u, rB1, 0);            // u2 (B NQ0)
    STAGE_B(0u, rB0 + 32, 0);      STAGE_B(0u, rB1 + 32, 0);       // u3 (B NQ1)
    STAGE_A(0u, 64 + wv * 8, 0);   STAGE_A(0u, 192 + wv * 8, 0);   // u1 (A MQ1)
    VMCNT(4);  // u0,u2 retired; outstanding = u3,u1 (4)
    BARRIER;
    // pre-issue Q00 reads for tile 0 (read-ahead steady-state entry)
    LOAD_AS(a0F0, a0F1, 0, 0u);
    LOAD_BS(0, 0u);

    for (int kt = 0; kt < NT; ++kt) {
        const bool haveNext = (kt + 1) < NT;
        const unsigned bufR = (kt & 1) ? 32768u : 0u;
        const unsigned bufW = ((kt + 1) & 1) ? 32768u : 0u;
        const int kc = (kt + 1) * 64;

        // ---- P1: stage u0'; gate u3; read B1; MFMA Q00 ----
        if (haveNext) {
            STAGE_A(bufW, wv * 8, kc); STAGE_A(bufW, 128 + wv * 8, kc);
            VMCNT(4);
        } else {
            VMCNT(2);
        }
        BARRIER;
        LOAD_BS(1, bufR);
        MFMA_Q(a0F0, a0F1, 0, 0);

        // ---- P2: stage u2'; gate u1; read A1; MFMA Q01 ----
        if (haveNext) {
            STAGE_B(bufW, rB0, kc); STAGE_B(bufW, rB1, kc);
            VMCNT(4);
        } else {
            VMCNT(0);
        }
        BARRIER;
        LOAD_AS(a1F0, a1F1, 1, bufR);
        MFMA_Q(a0F0, a0F1, 0, 1);

        // ---- P3: stage u3'; MFMA Q10 (no gate, no barrier) ----
        if (haveNext) { STAGE_B(bufW, rB0 + 32, kc); STAGE_B(bufW, rB1 + 32, kc); }
        MFMA_Q(a1F0, a1F1, 1, 0);

        // ---- P4: stage u1'; gate u0',u2'; read-ahead next A0,B0 from bufW; MFMA Q11 ----
        if (haveNext) {
            STAGE_A(bufW, 64 + wv * 8, kc); STAGE_A(bufW, 192 + wv * 8, kc);
            VMCNT(4);
            BARRIER;
            LOAD_AS(a0F0, a0F1, 0, bufW);
            LOAD_BS(0, bufW);
        }
        MFMA_Q(a1F0, a1F1, 1, 1);
    }

    // epilogue: C/D layout col = lane&15, row = (lane>>4)*4 + reg
    const int rbase = by * 256 + wr * 128;
    const int cbase = bx * 256 + wcn * 64;
    unsigned int* rm = rowmax + t * B_N;

    // row-max over this wave's 64 cols (diag excluded)
#pragma unroll
    for (int m = 0; m < 8; ++m) {
#pragma unroll
        for (int r = 0; r < 4; ++r) {
            const int row = rbase + m * 16 + (lane >> 4) * 4 + r;
            float mx = -2.0f;
#pragma unroll
            for (int n = 0; n < 4; ++n) {
                const int col = cbase + n * 16 + (lane & 15);
                float v = acc[m][n][r];
                if (col != row) mx = fmaxf(mx, v);
            }
#pragma unroll
            for (int off = 1; off < 16; off <<= 1) mx = fmaxf(mx, __shfl_xor(mx, off, 64));
            if ((lane & 15) == 0) atomicMax(&rm[row], f2u_ord(mx));
        }
    }
    // col-max over this wave's 128 rows (covers mirrored lower-triangle block)
#pragma unroll
    for (int n = 0; n < 4; ++n) {
        const int col = cbase + n * 16 + (lane & 15);
        float mx = -2.0f;
#pragma unroll
        for (int m = 0; m < 8; ++m)
#pragma unroll
            for (int r = 0; r < 4; ++r) {
                const int row = rbase + m * 16 + (lane >> 4) * 4 + r;
                float v = acc[m][n][r];
                if (col != row) mx = fmaxf(mx, v);
            }
        mx = fmaxf(mx, __shfl_xor(mx, 16, 64));
        mx = fmaxf(mx, __shfl_xor(mx, 32, 64));
        if ((lane >> 4) == 0) atomicMax(&rm[col], f2u_ord(mx));
    }
#undef MFMA_Q
#undef LOAD_AS
#undef LOAD_BS
#undef STAGE_A
#undef STAGE_B
#undef BARRIER
#undef VMCNT
}

__global__ __launch_bounds__(256) void finish_kernel(const unsigned int* __restrict__ rowmax,
                                                     float* __restrict__ out) {
    __shared__ float sbuf[4];
    float s = 0.f;
    for (int i = threadIdx.x; i < T_N * B_N; i += 256) {
        float m  = u2f_ord(rowmax[i]);
        float d2 = fmaxf(2.0f - 2.0f * m, 0.0f);
        s += logf(sqrtf(d2) + 1e-12f);
    }
#pragma unroll
    for (int off = 32; off; off >>= 1) s += __shfl_xor(s, off, 64);
    const int w = threadIdx.x >> 6;
    if ((threadIdx.x & 63) == 0) sbuf[w] = s;
    __syncthreads();
    if (threadIdx.x == 0) {
        out[0] = -(sbuf[0] + sbuf[1] + sbuf[2] + sbuf[3]) / (float)(T_N * B_N);
    }
}

extern "C" void kernel_launch(void* const* d_in, const int* in_sizes, int n_in,
                              void* d_out, int out_size, void* d_ws, size_t ws_size,
                              hipStream_t stream) {
    const float* in = (const float*)d_in[0];
    unsigned short* xn = (unsigned short*)d_ws;  // 64 MB bf16 [T][B][D]
    unsigned int* rowmax = (unsigned int*)((char*)d_ws + (size_t)T_N * B_N * D_N * 2);
    float* out = (float*)d_out;

    init_rowmax_kernel<<<(T_N * B_N + 255) / 256, 256, 0, stream>>>(rowmax);
    norm_kernel<<<(B_N * T_N) / 4, 256, 0, stream>>>(in, xn);
    dim3 g(TRI, 1, T_N);
    gemm_rowmax_kernel<<<g, 512, 0, stream>>>(xn, rowmax);
    finish_kernel<<<1, 256, 0, stream>>>(rowmax, out);
}

// Round 9
// 351.474 us; speedup vs baseline: 1.2270x; 1.2096x over previous
//
#include <hip/hip_runtime.h>
#include <hip/hip_bf16.h>
#include <math.h>

#define B_N 8192
#define T_N 4
#define D_N 1024
#define NB  32                 // 8192/256 blocks per dim
#define NT  16                 // 1024/64 K-tiles (64 fp8 bytes per tile-row)
#define TRI (NB * (NB + 1) / 2)  // 528 = 8*66

typedef float f32x4 __attribute__((ext_vector_type(4)));

// ---- order-preserving float <-> uint map ----
__device__ inline unsigned int f2u_ord(float f) {
    unsigned int b = __float_as_uint(f);
    return (b & 0x80000000u) ? ~b : (b | 0x80000000u);
}
__device__ inline float u2f_ord(unsigned int u) {
    unsigned int b = (u & 0x80000000u) ? (u & 0x7FFFFFFFu) : ~u;
    return __uint_as_float(b);
}

// f32 -> OCP e4m3fn, RNE. Valid for finite |x| < 2 (ours: |x| <= ~1).
__device__ inline unsigned int f2e4m3(float f) {
    unsigned int u = __float_as_uint(f);
    unsigned int sgn = (u >> 24) & 0x80u;
    int e = (int)((u >> 23) & 0xFFu) - 127;
    unsigned int m = u & 0x7FFFFFu;
    if (e >= -6) {  // normal fp8 range (bias 7)
        unsigned int mant = m >> 20;
        unsigned int rest = m & 0xFFFFFu;
        mant += (rest > 0x80000u) || (rest == 0x80000u && (mant & 1u));
        unsigned int exp8 = (unsigned)(e + 7);
        if (mant == 8u) { mant = 0u; exp8 += 1u; }
        return sgn | (exp8 << 3) | mant;
    } else {        // subnormal: quantum 2^-9
        float a = fabsf(f) * 512.0f;
        int q = (int)rintf(a);
        if (q >= 8) return sgn | 0x08u;
        return sgn | (unsigned)q;
    }
}

__global__ __launch_bounds__(256) void init_rowmax_kernel(unsigned int* __restrict__ rowmax) {
    int i = blockIdx.x * 256 + threadIdx.x;
    if (i < T_N * B_N) rowmax[i] = 0u;
}

// in: [B][T][D] f32 ; out xn: [T][B][D] fp8 e4m3 (normalized rows)
__global__ __launch_bounds__(256) void norm_kernel(const float* __restrict__ in,
                                                   unsigned char* __restrict__ xn) {
    const int row  = blockIdx.x * 4 + (threadIdx.x >> 6);
    const int lane = threadIdx.x & 63;
    const int b = row >> 2;
    const int t = row & 3;
    const float* src = in + (size_t)row * D_N;

    float4 v[4];
    float ss = 0.f;
#pragma unroll
    for (int i = 0; i < 4; ++i) {
        v[i] = reinterpret_cast<const float4*>(src)[lane + 64 * i];
        ss += v[i].x * v[i].x + v[i].y * v[i].y + v[i].z * v[i].z + v[i].w * v[i].w;
    }
#pragma unroll
    for (int off = 32; off; off >>= 1) ss += __shfl_xor(ss, off, 64);
    const float rn = 1.0f / fmaxf(sqrtf(ss), 1e-12f);

    unsigned int* dst = reinterpret_cast<unsigned int*>(xn + ((size_t)t * B_N + b) * D_N);
#pragma unroll
    for (int i = 0; i < 4; ++i) {
        unsigned int p = f2e4m3(v[i].x * rn) | (f2e4m3(v[i].y * rn) << 8) |
                         (f2e4m3(v[i].z * rn) << 16) | (f2e4m3(v[i].w * rn) << 24);
        dst[lane + 64 * i] = p;
    }
}

#define GLOAD_LDS16(g, l)                                                              \
    __builtin_amdgcn_global_load_lds(                                                  \
        (const __attribute__((address_space(1))) unsigned int*)(g),                    \
        (__attribute__((address_space(3))) unsigned int*)(l), 16, 0, 0)

// Gram upper-triangle, fp8 e4m3, 256x256 tile, BK=64B, 16 waves (4M x 4N grid,
// 64x64 C per wave, 64 AGPR acc). Triple-buffered LDS (3 x [A 16K | B 16K]),
// stage horizon 2 tiles: body(kt) = { BARRIER; stage(kt+2); 16 ds_read_b64 +
// 32 fp8-MFMA; vmcnt(2) }. One barrier + one counted gate per K-tile; loads get
// ~2 bodies to land. Super-row swizzle pos' = ((row&1)*4+chunk) ^ ((row>>1)&7):
// inverse-applied on per-lane global source (linear gload dest), same on reads.
__global__ __launch_bounds__(1024) void gemm_rowmax_kernel(const unsigned char* __restrict__ xn,
                                                           unsigned int* __restrict__ rowmax) {
    const int t = blockIdx.z;
    // XCD-chunked bijective swizzle (528 = 8*66)
    const int bid = blockIdx.x;
    int l = (bid & 7) * (TRI / 8) + (bid >> 3);
    int by = 0;
    while (l >= NB - by) { l -= NB - by; ++by; }
    const int bx = by + l;

    const unsigned char* X = xn + (size_t)t * B_N * D_N;

    __shared__ __align__(16) unsigned char lds[98304];  // 3 bufs x (A 16K + B 16K)

    const int tid  = threadIdx.x;
    const int lane = tid & 63;
    const int wv   = tid >> 6;   // 0..15
    const int wm   = wv >> 2;    // M quarter (64 rows)
    const int wn   = wv & 3;     // N quarter (64 cols)

    // ---- staging source (per lane), inverse-swizzled ----
    // dest slot: r = wv*16 + (lane>>2), c = lane&3  (linear: lane*16 within wave's 1KiB)
    {
    }
    const int sr  = wv * 16 + (lane >> 2);
    const int sc  = lane & 3;
    const int pd  = (((sr & 1) << 2) | sc) ^ ((sr >> 1) & 7);
    const int rp  = (sr & ~1) | (pd >> 2);
    const int cp  = (pd & 3) * 16;
    const unsigned char* gA = X + (size_t)(by * 256 + rp) * D_N + cp;
    const unsigned char* gB = X + (size_t)(bx * 256 + rp) * D_N + cp;

    // ---- fragment read lane offsets (swizzled), kk32 = 0 / 1 ----
    const unsigned s7  = (lane >> 1) & 7;
    const unsigned hi  = lane >> 5;          // chunk low bit
    const unsigned sub = (lane >> 4) & 1;    // 8B half of 16B chunk
    const unsigned b01 = lane & 1;
    const unsigned rowq = ((lane & 15) >> 1) * 128 + sub * 8;
    const unsigned lo0 = rowq + (((b01 << 2) | hi) ^ s7) * 16;
    const unsigned lo1 = rowq + (((b01 << 2) | 2 | hi) ^ s7) * 16;

    f32x4 acc[4][4];
#pragma unroll
    for (int m = 0; m < 4; ++m)
#pragma unroll
        for (int n = 0; n < 4; ++n) acc[m][n] = (f32x4){0.f, 0.f, 0.f, 0.f};

#define BARRIER asm volatile("s_barrier" ::: "memory")
#define VMCNT(N) asm volatile("s_waitcnt vmcnt(" #N ")" ::: "memory")

    // prologue: stage tile 0 -> buf0, tile 1 -> buf1; gate tile 0
    GLOAD_LDS16(gA, &lds[wv * 1024u]);
    GLOAD_LDS16(gB, &lds[16384u + wv * 1024u]);
    GLOAD_LDS16(gA + 64, &lds[32768u + wv * 1024u]);
    GLOAD_LDS16(gB + 64, &lds[32768u + 16384u + wv * 1024u]);
    VMCNT(2);  // tile 0 staged (per-wave); barrier in body(0) makes it collective

    int cur = 0;  // kt % 3
    for (int kt = 0; kt < NT; ++kt) {
        BARRIER;  // all waves: tile kt staged (their gate ran pre-barrier), prior reads done

        // stage tile kt+2 into buf (kt+2)%3 (last read at tile kt-1: safe)
        if (kt + 2 < NT) {
            int n2 = cur - 1; if (n2 < 0) n2 += 3;   // (cur+2)%3
            const unsigned sb = (unsigned)n2 * 32768u;
            GLOAD_LDS16(gA + (kt + 2) * 64, &lds[sb + wv * 1024u]);
            GLOAD_LDS16(gB + (kt + 2) * 64, &lds[sb + 16384u + wv * 1024u]);
        }

        const unsigned bb = (unsigned)cur * 32768u;

        long bK0[4], bK1[4];
#pragma unroll
        for (int nf = 0; nf < 4; ++nf) {
            const unsigned rB = bb + 16384u + (unsigned)wn * 4096u + (unsigned)nf * 1024u;
            bK0[nf] = *reinterpret_cast<const long*>(&lds[rB + lo0]);
            bK1[nf] = *reinterpret_cast<const long*>(&lds[rB + lo1]);
        }
        __builtin_amdgcn_s_setprio(1);
#pragma unroll
        for (int mf = 0; mf < 4; ++mf) {
            const unsigned rA = bb + (unsigned)wm * 4096u + (unsigned)mf * 1024u;
            long aK0 = *reinterpret_cast<const long*>(&lds[rA + lo0]);
            long aK1 = *reinterpret_cast<const long*>(&lds[rA + lo1]);
#pragma unroll
            for (int nf = 0; nf < 4; ++nf) {
                acc[mf][nf] = __builtin_amdgcn_mfma_f32_16x16x32_fp8_fp8(
                    aK0, bK0[nf], acc[mf][nf], 0, 0, 0);
                acc[mf][nf] = __builtin_amdgcn_mfma_f32_16x16x32_fp8_fp8(
                    aK1, bK1[nf], acc[mf][nf], 0, 0, 0);
            }
        }
        __builtin_amdgcn_s_setprio(0);

        // gate: retire tile kt+1's stages (issued last body), keep kt+2's in flight
        if (kt < NT - 2) { VMCNT(2); } else { VMCNT(0); }

        cur = (cur == 2) ? 0 : cur + 1;
    }

    // epilogue: C/D layout col = lane&15, row = (lane>>4)*4 + reg (dtype-independent)
    const int rbase = by * 256 + wm * 64;
    const int cbase = bx * 256 + wn * 64;
    unsigned int* rm = rowmax + t * B_N;

    // row-max over this wave's 64 cols (diag excluded)
#pragma unroll
    for (int m = 0; m < 4; ++m) {
#pragma unroll
        for (int r = 0; r < 4; ++r) {
            const int row = rbase + m * 16 + (lane >> 4) * 4 + r;
            float mx = -2.0f;
#pragma unroll
            for (int n = 0; n < 4; ++n) {
                const int col = cbase + n * 16 + (lane & 15);
                float v = acc[m][n][r];
                if (col != row) mx = fmaxf(mx, v);
            }
#pragma unroll
            for (int off = 1; off < 16; off <<= 1) mx = fmaxf(mx, __shfl_xor(mx, off, 64));
            if ((lane & 15) == 0) atomicMax(&rm[row], f2u_ord(mx));
        }
    }
    // col-max over this wave's 64 rows (covers mirrored lower-triangle block)
#pragma unroll
    for (int n = 0; n < 4; ++n) {
        const int col = cbase + n * 16 + (lane & 15);
        float mx = -2.0f;
#pragma unroll
        for (int m = 0; m < 4; ++m)
#pragma unroll
            for (int r = 0; r < 4; ++r) {
                const int row = rbase + m * 16 + (lane >> 4) * 4 + r;
                float v = acc[m][n][r];
                if (col != row) mx = fmaxf(mx, v);
            }
        mx = fmaxf(mx, __shfl_xor(mx, 16, 64));
        mx = fmaxf(mx, __shfl_xor(mx, 32, 64));
        if ((lane >> 4) == 0) atomicMax(&rm[col], f2u_ord(mx));
    }
#undef BARRIER
#undef VMCNT
}

__global__ __launch_bounds__(256) void finish_kernel(const unsigned int* __restrict__ rowmax,
                                                     float* __restrict__ out) {
    __shared__ float sbuf[4];
    float s = 0.f;
    for (int i = threadIdx.x; i < T_N * B_N; i += 256) {
        float m  = u2f_ord(rowmax[i]);
        float d2 = fmaxf(2.0f - 2.0f * m, 0.0f);
        s += logf(sqrtf(d2) + 1e-12f);
    }
#pragma unroll
    for (int off = 32; off; off >>= 1) s += __shfl_xor(s, off, 64);
    const int w = threadIdx.x >> 6;
    if ((threadIdx.x & 63) == 0) sbuf[w] = s;
    __syncthreads();
    if (threadIdx.x == 0) {
        out[0] = -(sbuf[0] + sbuf[1] + sbuf[2] + sbuf[3]) / (float)(T_N * B_N);
    }
}

extern "C" void kernel_launch(void* const* d_in, const int* in_sizes, int n_in,
                              void* d_out, int out_size, void* d_ws, size_t ws_size,
                              hipStream_t stream) {
    const float* in = (const float*)d_in[0];
    unsigned char* xn = (unsigned char*)d_ws;  // 32 MB fp8 [T][B][D]
    unsigned int* rowmax = (unsigned int*)((char*)d_ws + (size_t)T_N * B_N * D_N);
    float* out = (float*)d_out;

    init_rowmax_kernel<<<(T_N * B_N + 255) / 256, 256, 0, stream>>>(rowmax);
    norm_kernel<<<(B_N * T_N) / 4, 256, 0, stream>>>(in, xn);
    dim3 g(TRI, 1, T_N);
    gemm_rowmax_kernel<<<g, 1024, 0, stream>>>(xn, rowmax);
    finish_kernel<<<1, 256, 0, stream>>>(rowmax, out);
}

// Round 10
// 335.647 us; speedup vs baseline: 1.2849x; 1.0472x over previous
//
#include <hip/hip_runtime.h>
#include <hip/hip_bf16.h>
#include <math.h>

#define B_N 8192
#define T_N 4
#define D_N 1024
#define NB  32                 // 8192/256 blocks per dim
#define NT  16                 // 1024/64 K-tiles (64 fp8 bytes per tile-row)
#define TRI (NB * (NB + 1) / 2)  // 528 = 8*66

typedef float f32x4 __attribute__((ext_vector_type(4)));
typedef long longx2 __attribute__((ext_vector_type(2)));

// ---- order-preserving float <-> uint map ----
__device__ inline unsigned int f2u_ord(float f) {
    unsigned int b = __float_as_uint(f);
    return (b & 0x80000000u) ? ~b : (b | 0x80000000u);
}
__device__ inline float u2f_ord(unsigned int u) {
    unsigned int b = (u & 0x80000000u) ? (u & 0x7FFFFFFFu) : ~u;
    return __uint_as_float(b);
}

// f32 -> OCP e4m3fn, RNE. Valid for finite |x| < 2 (ours: |x| <= ~1).
__device__ inline unsigned int f2e4m3(float f) {
    unsigned int u = __float_as_uint(f);
    unsigned int sgn = (u >> 24) & 0x80u;
    int e = (int)((u >> 23) & 0xFFu) - 127;
    unsigned int m = u & 0x7FFFFFu;
    if (e >= -6) {  // normal fp8 range (bias 7)
        unsigned int mant = m >> 20;
        unsigned int rest = m & 0xFFFFFu;
        mant += (rest > 0x80000u) || (rest == 0x80000u && (mant & 1u));
        unsigned int exp8 = (unsigned)(e + 7);
        if (mant == 8u) { mant = 0u; exp8 += 1u; }
        return sgn | (exp8 << 3) | mant;
    } else {        // subnormal: quantum 2^-9
        float a = fabsf(f) * 512.0f;
        int q = (int)rintf(a);
        if (q >= 8) return sgn | 0x08u;
        return sgn | (unsigned)q;
    }
}

__global__ __launch_bounds__(256) void init_rowmax_kernel(unsigned int* __restrict__ rowmax) {
    int i = blockIdx.x * 256 + threadIdx.x;
    if (i < T_N * B_N) rowmax[i] = 0u;
}

// in: [B][T][D] f32 ; out xn: [T][B][D] fp8 e4m3 (normalized rows), UNIT-PAIRED:
// within each 64B K-block, 8B piece q (q=0..7) is stored at position
// ((q&3)<<1)|(q>>2)  -> 16B unit U holds pieces {U, U+4} = (k-half0, k-half1)
// for MFMA lane kq=U. Emitted here so GEMM staging reads are 16B-contiguous.
__global__ __launch_bounds__(256) void norm_kernel(const float* __restrict__ in,
                                                   unsigned char* __restrict__ xn) {
    const int row  = blockIdx.x * 4 + (threadIdx.x >> 6);
    const int lane = threadIdx.x & 63;
    const int b = row >> 2;
    const int t = row & 3;
    const float* src = in + (size_t)row * D_N;

    float4 v[4];
    float ss = 0.f;
#pragma unroll
    for (int i = 0; i < 4; ++i) {
        v[i] = reinterpret_cast<const float4*>(src)[lane + 64 * i];
        ss += v[i].x * v[i].x + v[i].y * v[i].y + v[i].z * v[i].z + v[i].w * v[i].w;
    }
#pragma unroll
    for (int off = 32; off; off >>= 1) ss += __shfl_xor(ss, off, 64);
    const float rn = 1.0f / fmaxf(sqrtf(ss), 1e-12f);

    unsigned int* dst = reinterpret_cast<unsigned int*>(xn + ((size_t)t * B_N + b) * D_N);
#pragma unroll
    for (int i = 0; i < 4; ++i) {
        unsigned int p = f2e4m3(v[i].x * rn) | (f2e4m3(v[i].y * rn) << 8) |
                         (f2e4m3(v[i].z * rn) << 16) | (f2e4m3(v[i].w * rn) << 24);
        // source word w (4 fp8 = 4B); piece q' = (w>>1)&3 + k-half (w>>3)&1
        const int w  = lane + 64 * i;
        const int pp = (((w >> 1) & 3) << 1) | ((w >> 3) & 1);   // permuted piece pos
        const int dw = (w & ~15) | (pp << 1) | (w & 1);
        dst[dw] = p;
    }
}

#define GLOAD_LDS16(g, l)                                                              \
    __builtin_amdgcn_global_load_lds(                                                  \
        (const __attribute__((address_space(1))) unsigned int*)(g),                    \
        (__attribute__((address_space(3))) unsigned int*)(l), 16, 0, 0)

// Gram upper-triangle, fp8 e4m3 (unit-paired layout), 256x256 tile, BK=64B,
// 16 waves (4M x 4N, 64x64 C per wave). Triple-buffered LDS, stage horizon 2:
// body(kt) = { BARRIER; stage(kt+2); 8 ds_read_b128 + 32 fp8-MFMA; vmcnt(2) }.
// LDS swizzle = R3-proven pattern: unit' = U ^ ((row>>2)&3), one b128 per
// fragment (low 8B = k-step0, high 8B = k-step1). Measured 0-conflict pattern.
__global__ __launch_bounds__(1024) void gemm_rowmax_kernel(const unsigned char* __restrict__ xn,
                                                           unsigned int* __restrict__ rowmax) {
    const int t = blockIdx.z;
    // XCD-chunked bijective swizzle (528 = 8*66)
    const int bid = blockIdx.x;
    int l = (bid & 7) * (TRI / 8) + (bid >> 3);
    int by = 0;
    while (l >= NB - by) { l -= NB - by; ++by; }
    const int bx = by + l;

    const unsigned char* X = xn + (size_t)t * B_N * D_N;

    __shared__ __align__(16) unsigned char lds[98304];  // 3 bufs x (A 16K + B 16K)

    const int tid  = threadIdx.x;
    const int lane = tid & 63;
    const int wv   = tid >> 6;   // 0..15
    const int wm   = wv >> 2;    // M quarter (64 rows)
    const int wn   = wv & 3;     // N quarter (64 cols)

    // ---- staging source (per lane): dest slot r = wv*16 + (lane>>2), pos p = lane&3
    // LDS pos p holds logical unit u = p ^ sigma(r), sigma(r) = (r>>2)&3 = (lane>>4)&3
    const int srow = wv * 16 + (lane >> 2);
    const int spos = (lane & 3) ^ ((lane >> 4) & 3);
    const unsigned char* gA = X + (size_t)(by * 256 + srow) * D_N + spos * 16;
    const unsigned char* gB = X + (size_t)(bx * 256 + srow) * D_N + spos * 16;

    // ---- fragment read offset: row r0 = lane&15, unit kq = lane>>4,
    // LDS pos = kq ^ ((r0>>2)&3) = (lane>>4) ^ ((lane>>2)&3)
    const unsigned rdoff = (unsigned)(lane & 15) * 64u +
                           (unsigned)(((lane >> 4) ^ ((lane >> 2) & 3)) & 3) * 16u;

    f32x4 acc[4][4];
#pragma unroll
    for (int m = 0; m < 4; ++m)
#pragma unroll
        for (int n = 0; n < 4; ++n) acc[m][n] = (f32x4){0.f, 0.f, 0.f, 0.f};

#define BARRIER asm volatile("s_barrier" ::: "memory")
#define VMCNT(N) asm volatile("s_waitcnt vmcnt(" #N ")" ::: "memory")

    // prologue: stage tile 0 -> buf0, tile 1 -> buf1; gate tile 0
    GLOAD_LDS16(gA, &lds[wv * 1024u]);
    GLOAD_LDS16(gB, &lds[16384u + wv * 1024u]);
    GLOAD_LDS16(gA + 64, &lds[32768u + wv * 1024u]);
    GLOAD_LDS16(gB + 64, &lds[32768u + 16384u + wv * 1024u]);
    VMCNT(2);  // tile 0 staged (per-wave); barrier in body(0) makes it collective

    int cur = 0;  // kt % 3
    for (int kt = 0; kt < NT; ++kt) {
        BARRIER;  // all waves: tile kt staged, prior-tile reads done

        // stage tile kt+2 into buf (kt+2)%3 (its last reads were at tile kt-1)
        if (kt + 2 < NT) {
            int n2 = cur - 1; if (n2 < 0) n2 += 3;   // (cur+2)%3
            const unsigned sb = (unsigned)n2 * 32768u;
            GLOAD_LDS16(gA + (kt + 2) * 64, &lds[sb + wv * 1024u]);
            GLOAD_LDS16(gB + (kt + 2) * 64, &lds[sb + 16384u + wv * 1024u]);
        }

        const unsigned bb = (unsigned)cur * 32768u;

        longx2 bV[4];
#pragma unroll
        for (int nf = 0; nf < 4; ++nf) {
            const unsigned rB = bb + 16384u + (unsigned)wn * 4096u + (unsigned)nf * 1024u + rdoff;
            bV[nf] = *reinterpret_cast<const longx2*>(&lds[rB]);
        }
        __builtin_amdgcn_s_setprio(1);
#pragma unroll
        for (int mf = 0; mf < 4; ++mf) {
            const unsigned rA = bb + (unsigned)wm * 4096u + (unsigned)mf * 1024u + rdoff;
            longx2 aV = *reinterpret_cast<const longx2*>(&lds[rA]);
#pragma unroll
            for (int nf = 0; nf < 4; ++nf) {
                acc[mf][nf] = __builtin_amdgcn_mfma_f32_16x16x32_fp8_fp8(
                    aV[0], bV[nf][0], acc[mf][nf], 0, 0, 0);
                acc[mf][nf] = __builtin_amdgcn_mfma_f32_16x16x32_fp8_fp8(
                    aV[1], bV[nf][1], acc[mf][nf], 0, 0, 0);
            }
        }
        __builtin_amdgcn_s_setprio(0);

        // gate: retire tile kt+1's stages (issued last body), keep kt+2's in flight
        if (kt < NT - 2) { VMCNT(2); } else { VMCNT(0); }

        cur = (cur == 2) ? 0 : cur + 1;
    }

    // epilogue: C/D layout col = lane&15, row = (lane>>4)*4 + reg (dtype-independent)
    const int rbase = by * 256 + wm * 64;
    const int cbase = bx * 256 + wn * 64;
    unsigned int* rm = rowmax + t * B_N;

    // row-max over this wave's 64 cols (diag excluded)
#pragma unroll
    for (int m = 0; m < 4; ++m) {
#pragma unroll
        for (int r = 0; r < 4; ++r) {
            const int row = rbase + m * 16 + (lane >> 4) * 4 + r;
            float mx = -2.0f;
#pragma unroll
            for (int n = 0; n < 4; ++n) {
                const int col = cbase + n * 16 + (lane & 15);
                float v = acc[m][n][r];
                if (col != row) mx = fmaxf(mx, v);
            }
#pragma unroll
            for (int off = 1; off < 16; off <<= 1) mx = fmaxf(mx, __shfl_xor(mx, off, 64));
            if ((lane & 15) == 0) atomicMax(&rm[row], f2u_ord(mx));
        }
    }
    // col-max over this wave's 64 rows (covers mirrored lower-triangle block)
#pragma unroll
    for (int n = 0; n < 4; ++n) {
        const int col = cbase + n * 16 + (lane & 15);
        float mx = -2.0f;
#pragma unroll
        for (int m = 0; m < 4; ++m)
#pragma unroll
            for (int r = 0; r < 4; ++r) {
                const int row = rbase + m * 16 + (lane >> 4) * 4 + r;
                float v = acc[m][n][r];
                if (col != row) mx = fmaxf(mx, v);
            }
        mx = fmaxf(mx, __shfl_xor(mx, 16, 64));
        mx = fmaxf(mx, __shfl_xor(mx, 32, 64));
        if ((lane >> 4) == 0) atomicMax(&rm[col], f2u_ord(mx));
    }
#undef BARRIER
#undef VMCNT
}

__global__ __launch_bounds__(256) void finish_kernel(const unsigned int* __restrict__ rowmax,
                                                     float* __restrict__ out) {
    __shared__ float sbuf[4];
    float s = 0.f;
    for (int i = threadIdx.x; i < T_N * B_N; i += 256) {
        float m  = u2f_ord(rowmax[i]);
        float d2 = fmaxf(2.0f - 2.0f * m, 0.0f);
        s += logf(sqrtf(d2) + 1e-12f);
    }
#pragma unroll
    for (int off = 32; off; off >>= 1) s += __shfl_xor(s, off, 64);
    const int w = threadIdx.x >> 6;
    if ((threadIdx.x & 63) == 0) sbuf[w] = s;
    __syncthreads();
    if (threadIdx.x == 0) {
        out[0] = -(sbuf[0] + sbuf[1] + sbuf[2] + sbuf[3]) / (float)(T_N * B_N);
    }
}

extern "C" void kernel_launch(void* const* d_in, const int* in_sizes, int n_in,
                              void* d_out, int out_size, void* d_ws, size_t ws_size,
                              hipStream_t stream) {
    const float* in = (const float*)d_in[0];
    unsigned char* xn = (unsigned char*)d_ws;  // 32 MB fp8 [T][B][D], unit-paired
    unsigned int* rowmax = (unsigned int*)((char*)d_ws + (size_t)T_N * B_N * D_N);
    float* out = (float*)d_out;

    init_rowmax_kernel<<<(T_N * B_N + 255) / 256, 256, 0, stream>>>(rowmax);
    norm_kernel<<<(B_N * T_N) / 4, 256, 0, stream>>>(in, xn);
    dim3 g(TRI, 1, T_N);
    gemm_rowmax_kernel<<<g, 1024, 0, stream>>>(xn, rowmax);
    finish_kernel<<<1, 256, 0, stream>>>(rowmax, out);
}

// Round 11
// 263.241 us; speedup vs baseline: 1.6383x; 1.2751x over previous
//
#include <hip/hip_runtime.h>
#include <hip/hip_bf16.h>
#include <math.h>

#define B_N 8192
#define T_N 4
#define D_N 1024
#define BM  128
#define BN  256
#define NT  16                 // 1024/64 K-tiles (64 fp8 bytes per tile-row)
#define NBLK 1056              // sum_{bx=0}^{31} (2bx+2) = 1056 = 8*132

typedef float f32x4 __attribute__((ext_vector_type(4)));
typedef long longx2 __attribute__((ext_vector_type(2)));

// ---- order-preserving float <-> uint map ----
__device__ inline unsigned int f2u_ord(float f) {
    unsigned int b = __float_as_uint(f);
    return (b & 0x80000000u) ? ~b : (b | 0x80000000u);
}
__device__ inline float u2f_ord(unsigned int u) {
    unsigned int b = (u & 0x80000000u) ? (u & 0x7FFFFFFFu) : ~u;
    return __uint_as_float(b);
}

// f32 -> OCP e4m3fn, RNE. Valid for finite |x| < 2 (ours: |x| <= ~1).
__device__ inline unsigned int f2e4m3(float f) {
    unsigned int u = __float_as_uint(f);
    unsigned int sgn = (u >> 24) & 0x80u;
    int e = (int)((u >> 23) & 0xFFu) - 127;
    unsigned int m = u & 0x7FFFFFu;
    if (e >= -6) {  // normal fp8 range (bias 7)
        unsigned int mant = m >> 20;
        unsigned int rest = m & 0xFFFFFu;
        mant += (rest > 0x80000u) || (rest == 0x80000u && (mant & 1u));
        unsigned int exp8 = (unsigned)(e + 7);
        if (mant == 8u) { mant = 0u; exp8 += 1u; }
        return sgn | (exp8 << 3) | mant;
    } else {        // subnormal: quantum 2^-9
        float a = fabsf(f) * 512.0f;
        int q = (int)rintf(a);
        if (q >= 8) return sgn | 0x08u;
        return sgn | (unsigned)q;
    }
}

__global__ __launch_bounds__(256) void init_rowmax_kernel(unsigned int* __restrict__ rowmax) {
    int i = blockIdx.x * 256 + threadIdx.x;
    if (i < T_N * B_N) rowmax[i] = 0u;
}

// in: [B][T][D] f32 ; out xn: [T][B][D] fp8 e4m3 (normalized rows), UNIT-PAIRED:
// within each 64B K-block, 8B piece q (q=0..7) stored at ((q&3)<<1)|(q>>2) ->
// 16B unit U holds pieces {U, U+4} = (k-half0, k-half1) for MFMA lane kq=U.
__global__ __launch_bounds__(256) void norm_kernel(const float* __restrict__ in,
                                                   unsigned char* __restrict__ xn) {
    const int row  = blockIdx.x * 4 + (threadIdx.x >> 6);
    const int lane = threadIdx.x & 63;
    const int b = row >> 2;
    const int t = row & 3;
    const float* src = in + (size_t)row * D_N;

    float4 v[4];
    float ss = 0.f;
#pragma unroll
    for (int i = 0; i < 4; ++i) {
        v[i] = reinterpret_cast<const float4*>(src)[lane + 64 * i];
        ss += v[i].x * v[i].x + v[i].y * v[i].y + v[i].z * v[i].z + v[i].w * v[i].w;
    }
#pragma unroll
    for (int off = 32; off; off >>= 1) ss += __shfl_xor(ss, off, 64);
    const float rn = 1.0f / fmaxf(sqrtf(ss), 1e-12f);

    unsigned int* dst = reinterpret_cast<unsigned int*>(xn + ((size_t)t * B_N + b) * D_N);
#pragma unroll
    for (int i = 0; i < 4; ++i) {
        unsigned int p = f2e4m3(v[i].x * rn) | (f2e4m3(v[i].y * rn) << 8) |
                         (f2e4m3(v[i].z * rn) << 16) | (f2e4m3(v[i].w * rn) << 24);
        const int w  = lane + 64 * i;
        const int pp = (((w >> 1) & 3) << 1) | ((w >> 3) & 1);   // permuted piece pos
        const int dw = (w & ~15) | (pp << 1) | (w & 1);
        dst[dw] = p;
    }
}

#define GLOAD_LDS16(g, l)                                                              \
    __builtin_amdgcn_global_load_lds(                                                  \
        (const __attribute__((address_space(1))) unsigned int*)(g),                    \
        (__attribute__((address_space(3))) unsigned int*)(l), 16, 0, 0)

// Gram upper-triangle, fp8 e4m3 (unit-paired), tile 128x256, BK=64B, 8 waves
// (2M x 4N, 64x64 C per wave), TWO blocks co-resident per CU (72KB LDS,
// launch_bounds(512,4) pins VGPR<=128 = 4 waves/SIMD): independent barrier
// groups fill each other's stall windows (m114 mechanism). Triple-buffered
// LDS, horizon-2 staging, 1 barrier + 1 counted vmcnt(3) per K-tile.
// LDS swizzle: unit' = U ^ ((row>>2)&3) (R3-proven b128 pattern, 2-way max).
__global__ __launch_bounds__(512, 4) void gemm_rowmax_kernel(const unsigned char* __restrict__ xn,
                                                             unsigned int* __restrict__ rowmax) {
    const int t = blockIdx.z;
    // XCD-chunked bijective swizzle (1056 = 8*132); each XCD gets a contiguous
    // bx range (Sum 2bx+2 over bx 0..10 = 132) -> B-panel stays in its L2.
    const int bid = blockIdx.x;
    int l = (bid & 7) * (NBLK / 8) + (bid >> 3);
    int bx = 0;
    while (l >= 2 * bx + 2) { l -= 2 * bx + 2; ++bx; }
    const int by = l;   // 0 .. 2bx+1  (128-row block; 256-col block bx)

    const unsigned char* X = xn + (size_t)t * B_N * D_N;

    __shared__ __align__(16) unsigned char lds[73728];  // 3 bufs x (A 8K + B 16K)

    const int tid  = threadIdx.x;
    const int lane = tid & 63;
    const int wv   = tid >> 6;   // 0..7
    const int wm   = wv >> 2;    // M half (64 rows)
    const int wn   = wv & 3;     // N quarter (64 cols)

    // staging source (per lane): dest slot row = wv*16 + (lane>>2), pos = lane&3;
    // LDS pos p holds unit u = p ^ ((row>>2)&3) -> source pos = (lane&3)^((lane>>4)&3)
    const int srow = lane >> 2;
    const int spos = (lane & 3) ^ ((lane >> 4) & 3);
    const unsigned char* gA  = X + (size_t)(by * BM + wv * 16 + srow) * D_N + spos * 16;
    const unsigned char* gB0 = X + (size_t)(bx * BN + wv * 16 + srow) * D_N + spos * 16;
    const unsigned char* gB1 = gB0 + (size_t)128 * D_N;

    // fragment read: row r0 = lane&15, unit kq = lane>>4, pos = kq ^ ((r0>>2)&3)
    const unsigned rdoff = (unsigned)(lane & 15) * 64u +
                           (unsigned)(((lane >> 4) ^ (lane >> 2)) & 3) * 16u;

    f32x4 acc[4][4];
#pragma unroll
    for (int m = 0; m < 4; ++m)
#pragma unroll
        for (int n = 0; n < 4; ++n) acc[m][n] = (f32x4){0.f, 0.f, 0.f, 0.f};

#define BARRIER asm volatile("s_barrier" ::: "memory")
#define VMCNT(N) asm volatile("s_waitcnt vmcnt(" #N ")" ::: "memory")
#define STAGE(buf, kc)                                                                  \
    GLOAD_LDS16(gA + (kc),  &lds[(buf) + wv * 1024u]);                                  \
    GLOAD_LDS16(gB0 + (kc), &lds[(buf) + 8192u + wv * 1024u]);                          \
    GLOAD_LDS16(gB1 + (kc), &lds[(buf) + 16384u + wv * 1024u]);

    // prologue: stage tile 0 -> buf0, tile 1 -> buf1; gate tile 0
    STAGE(0u, 0)
    STAGE(24576u, 64)
    VMCNT(3);  // tile 0 staged (per-wave); barrier in body(0) makes it collective

    int cur = 0;  // kt % 3
    for (int kt = 0; kt < NT; ++kt) {
        BARRIER;  // all waves: tile kt staged, prior-tile reads done

        if (kt + 2 < NT) {
            int n2 = cur - 1; if (n2 < 0) n2 += 3;   // (cur+2)%3
            STAGE((unsigned)n2 * 24576u, (kt + 2) * 64)
        }

        const unsigned bb = (unsigned)cur * 24576u;

        longx2 bV[4];
#pragma unroll
        for (int nf = 0; nf < 4; ++nf) {
            const unsigned rB = bb + 8192u + (unsigned)wn * 4096u + (unsigned)nf * 1024u + rdoff;
            bV[nf] = *reinterpret_cast<const longx2*>(&lds[rB]);
        }
        __builtin_amdgcn_s_setprio(1);
#pragma unroll
        for (int mf = 0; mf < 4; ++mf) {
            const unsigned rA = bb + (unsigned)wm * 4096u + (unsigned)mf * 1024u + rdoff;
            longx2 aV = *reinterpret_cast<const longx2*>(&lds[rA]);
#pragma unroll
            for (int nf = 0; nf < 4; ++nf) {
                acc[mf][nf] = __builtin_amdgcn_mfma_f32_16x16x32_fp8_fp8(
                    aV[0], bV[nf][0], acc[mf][nf], 0, 0, 0);
                acc[mf][nf] = __builtin_amdgcn_mfma_f32_16x16x32_fp8_fp8(
                    aV[1], bV[nf][1], acc[mf][nf], 0, 0, 0);
            }
        }
        __builtin_amdgcn_s_setprio(0);

        // gate: retire tile kt+1's stages (issued last body), keep kt+2's in flight
        if (kt < NT - 2) { VMCNT(3); } else { VMCNT(0); }

        cur = (cur == 2) ? 0 : cur + 1;
    }

    // epilogue: C/D layout col = lane&15, row = (lane>>4)*4 + reg
    const int rbase = by * BM + wm * 64;
    const int cbase = bx * BN + wn * 64;
    unsigned int* rm = rowmax + t * B_N;

    // row-max over this wave's 64 cols (diag excluded)
#pragma unroll
    for (int m = 0; m < 4; ++m) {
#pragma unroll
        for (int r = 0; r < 4; ++r) {
            const int row = rbase + m * 16 + (lane >> 4) * 4 + r;
            float mx = -2.0f;
#pragma unroll
            for (int n = 0; n < 4; ++n) {
                const int col = cbase + n * 16 + (lane & 15);
                float v = acc[m][n][r];
                if (col != row) mx = fmaxf(mx, v);
            }
#pragma unroll
            for (int off = 1; off < 16; off <<= 1) mx = fmaxf(mx, __shfl_xor(mx, off, 64));
            if ((lane & 15) == 0) atomicMax(&rm[row], f2u_ord(mx));
        }
    }
    // col-max over this wave's 64 rows (covers mirrored lower-triangle part)
#pragma unroll
    for (int n = 0; n < 4; ++n) {
        const int col = cbase + n * 16 + (lane & 15);
        float mx = -2.0f;
#pragma unroll
        for (int m = 0; m < 4; ++m)
#pragma unroll
            for (int r = 0; r < 4; ++r) {
                const int row = rbase + m * 16 + (lane >> 4) * 4 + r;
                float v = acc[m][n][r];
                if (col != row) mx = fmaxf(mx, v);
            }
        mx = fmaxf(mx, __shfl_xor(mx, 16, 64));
        mx = fmaxf(mx, __shfl_xor(mx, 32, 64));
        if ((lane >> 4) == 0) atomicMax(&rm[col], f2u_ord(mx));
    }
#undef BARRIER
#undef VMCNT
#undef STAGE
}

__global__ __launch_bounds__(256) void finish_kernel(const unsigned int* __restrict__ rowmax,
                                                     float* __restrict__ out) {
    __shared__ float sbuf[4];
    float s = 0.f;
    for (int i = threadIdx.x; i < T_N * B_N; i += 256) {
        float m  = u2f_ord(rowmax[i]);
        float d2 = fmaxf(2.0f - 2.0f * m, 0.0f);
        s += logf(sqrtf(d2) + 1e-12f);
    }
#pragma unroll
    for (int off = 32; off; off >>= 1) s += __shfl_xor(s, off, 64);
    const int w = threadIdx.x >> 6;
    if ((threadIdx.x & 63) == 0) sbuf[w] = s;
    __syncthreads();
    if (threadIdx.x == 0) {
        out[0] = -(sbuf[0] + sbuf[1] + sbuf[2] + sbuf[3]) / (float)(T_N * B_N);
    }
}

extern "C" void kernel_launch(void* const* d_in, const int* in_sizes, int n_in,
                              void* d_out, int out_size, void* d_ws, size_t ws_size,
                              hipStream_t stream) {
    const float* in = (const float*)d_in[0];
    unsigned char* xn = (unsigned char*)d_ws;  // 32 MB fp8 [T][B][D], unit-paired
    unsigned int* rowmax = (unsigned int*)((char*)d_ws + (size_t)T_N * B_N * D_N);
    float* out = (float*)d_out;

    init_rowmax_kernel<<<(T_N * B_N + 255) / 256, 256, 0, stream>>>(rowmax);
    norm_kernel<<<(B_N * T_N) / 4, 256, 0, stream>>>(in, xn);
    dim3 g(NBLK, 1, T_N);
    gemm_rowmax_kernel<<<g, 512, 0, stream>>>(xn, rowmax);
    finish_kernel<<<1, 256, 0, stream>>>(rowmax, out);
}